// Round 10
// baseline (246.693 us; speedup 1.0000x reference)
//
#include <hip/hip_runtime.h>
#include <math.h>

// HuberEMA: y[t] = y[t-1] + (1-a[c]) * clamp(x[t]-y[t-1], -d, +d); y[0] = x[0]
// B=32, T=2048, C=512 fp32. 16384 chains -> 256 blocks, 64 chains/block.
// Roofline: 268 MB => ~43 us @ 6.3 TB/s (1600 cyc per 16 KB tile per CU).
//
// R9 (wave specialization, RING=4): 110 -> 84.6 us. Split vmcnt FIFOs fixed
// the store-ack drain, but both streams run at ~2.5 B/cyc/CU = half the m13
// copy rate. Diagnosis H-B: only 16 KB of loads in flight per CU for most
// of each period -- too shallow for loaded HBM latency (m13's 6.3 TB/s was
// measured with far more in-flight bytes per CU). This round: RING 4 -> 8,
// producer issues tile k+7, steady outstanding = 56 DMA ops = 56 KB/CU
// (3.5x deeper, < 63-op vmcnt cap). Wait ladder recomputed; nothing else
// changed (single-variable discipline).
//
// Roles (3 waves/block): w0 producer = DMA + counted vmcnt only (FIFO holds
// ONLY x loads); w1 consumer = zero loop VMEM (ds_read xin, serial chain,
// ds_write y); w2 storer = ds_read y -> coalesced dwordx4 stores (store
// acks never waited). Raw s_barrier (NOT __syncthreads: that drains
// vmcnt(0)); sched_barrier(0) fences per rule #18.

#define TT   2048
#define CC   512
#define TILE 32
#define NTIL (TT / TILE)   // 64 tiles
#define LPT  8             // 1 KB global_load_lds ops per tile (8 KB tile)
#define RING 8             // ring depth: 7-tile lookahead, 56 ops in flight

__device__ __forceinline__ void async16(const float* g, float* l) {
    // 64 lanes x 16 B: per-lane global src, wave-uniform LDS dst (+lane*16)
    __builtin_amdgcn_global_load_lds(
        (const __attribute__((address_space(1))) void*)g,
        (__attribute__((address_space(3))) void*)l, 16, 0, 0);
}

template<int N> __device__ __forceinline__ void vm_wait() {
    if constexpr (N == 0)       asm volatile("s_waitcnt vmcnt(0)"  ::: "memory");
    else if constexpr (N == 8)  asm volatile("s_waitcnt vmcnt(8)"  ::: "memory");
    else if constexpr (N == 16) asm volatile("s_waitcnt vmcnt(16)" ::: "memory");
    else if constexpr (N == 24) asm volatile("s_waitcnt vmcnt(24)" ::: "memory");
    else if constexpr (N == 32) asm volatile("s_waitcnt vmcnt(32)" ::: "memory");
    else if constexpr (N == 40) asm volatile("s_waitcnt vmcnt(40)" ::: "memory");
    else if constexpr (N == 48) asm volatile("s_waitcnt vmcnt(48)" ::: "memory");
    __builtin_amdgcn_sched_barrier(0);
}

__device__ __forceinline__ void lgkm0() {
    asm volatile("s_waitcnt lgkmcnt(0)" ::: "memory");
    __builtin_amdgcn_sched_barrier(0);
}

__device__ __forceinline__ void bar() {
    __builtin_amdgcn_sched_barrier(0);
    __builtin_amdgcn_s_barrier();
    __builtin_amdgcn_sched_barrier(0);
}

__global__ __launch_bounds__(192, 1)
void huber_ema_kernel(const float* __restrict__ x,
                      const float* __restrict__ logit_alpha,
                      const float* __restrict__ delta,
                      float* __restrict__ y)
{
    const int blk  = blockIdx.x;     // 0..255
    const int b    = blk >> 3;       // batch
    const int cc   = blk & 7;        // 64-wide channel chunk
    const int tid  = threadIdx.x;
    const int lane = tid & 63;
    const int wid  = tid >> 6;       // 0=producer 1=consumer 2=storer

    __shared__ float xs[RING][TILE * 64];   // 8 x 8 KB x ring (64 KB)
    __shared__ float ys[2][TILE * 64];      // 2 x 8 KB y double buffer

    const float* __restrict__ xb = x + (size_t)b * TT * CC + (cc << 6);
    float*       __restrict__ yb = y + (size_t)b * TT * CC + (cc << 6);
    // packed mapping (validated R6/R9, absmax=0): instr g covers t rows
    // g*4..g*4+3; lane -> row lane>>4, channels (lane&15)*4..+3
    const float* __restrict__ xl = xb + (size_t)(lane >> 4) * CC + ((lane & 15) << 2);
    float*       __restrict__ yl = yb + (size_t)(lane >> 4) * CC + ((lane & 15) << 2);

    // consumer-only state
    float yv = 0.f, oma = 0.f, d = 0.f;

    if (wid == 0) {
        // prologue: DMA tiles 0..6 (56 ops); wait tile 0 landed (56->48)
        #pragma unroll
        for (int t = 0; t < RING - 1; ++t) {
            #pragma unroll
            for (int g = 0; g < LPT; ++g)
                async16(xl + (size_t)(t * TILE + g * 4) * CC, &xs[t][g * 256]);
        }
        vm_wait<48>();
    } else if (wid == 1) {
        const float la = logit_alpha[(cc << 6) + lane];
        d  = delta[0];
        yv = xb[lane];               // y[-1] := x[0]; step 0 -> y0 = x0 exact
        float a = 1.0f / (1.0f + expf(-la));
        a = fminf(fmaxf(a, 1e-4f), 1.0f - 1e-4f);
        oma = 1.0f - a;
    }
    bar();   // B0: tile 0 in LDS

    for (int k = 0; k < NTIL; ++k) {
        if (wid == 0) {
            // issue tile k+7 into slot (k+7)&7 (= slot consumer freed at
            // k-1); counted wait -> tile k+1 is in LDS by the barrier.
            // Invariant at loop top: outstanding = tiles k+1..k+6 (48 ops).
            if (k + RING - 1 < NTIL) {
                #pragma unroll
                for (int g = 0; g < LPT; ++g)
                    async16(xl + (size_t)((k + RING - 1) * TILE + g * 4) * CC,
                            &xs[(k + RING - 1) & (RING - 1)][g * 256]);
                vm_wait<48>();          // 56 outstanding -> tile k+1 done
            }
            else if (k == NTIL - 7) { vm_wait<40>(); }
            else if (k == NTIL - 6) { vm_wait<32>(); }
            else if (k == NTIL - 5) { vm_wait<24>(); }
            else if (k == NTIL - 4) { vm_wait<16>(); }
            else if (k == NTIL - 3) { vm_wait<8>();  }
            else if (k == NTIL - 2) { vm_wait<0>();  }
            // k == NTIL-1: nothing outstanding
        } else if (wid == 1) {
            const float* __restrict__ bx = xs[k & (RING - 1)];
            float*       __restrict__ by = ys[k & 1];
            float xin[TILE];
            #pragma unroll
            for (int i = 0; i < TILE; ++i) xin[i] = bx[i * 64 + lane];
            __builtin_amdgcn_sched_barrier(0);
            #pragma unroll
            for (int i = 0; i < TILE; ++i) {
                float r = xin[i] - yv;
                yv += oma * fminf(fmaxf(r, -d), d);
                by[i * 64 + lane] = yv;
            }
            lgkm0();                    // y writes visible before barrier
        } else {
            if (k > 0) {                // store tile k-1 from ys[(k-1)&1]
                const float* __restrict__ sy = ys[(k - 1) & 1];
                const size_t tb = (size_t)(k - 1) * TILE;
                #pragma unroll
                for (int g = 0; g < LPT; ++g) {
                    float4 v = *(const float4*)&sy[g * 256 + (lane << 2)];
                    *(float4*)(yl + (tb + (size_t)(g * 4)) * CC) = v;
                }
            }
        }
        bar();
    }

    // epilogue: storer writes the final tile (consumer's lgkm0 + last bar
    // made it visible); other waves simply exit
    if (wid == 2) {
        const float* __restrict__ sy = ys[(NTIL - 1) & 1];
        const size_t tb = (size_t)(NTIL - 1) * TILE;
        #pragma unroll
        for (int g = 0; g < LPT; ++g) {
            float4 v = *(const float4*)&sy[g * 256 + (lane << 2)];
            *(float4*)(yl + (tb + (size_t)(g * 4)) * CC) = v;
        }
    }
}

extern "C" void kernel_launch(void* const* d_in, const int* in_sizes, int n_in,
                              void* d_out, int out_size, void* d_ws, size_t ws_size,
                              hipStream_t stream) {
    const float* x  = (const float*)d_in[0];
    const float* la = (const float*)d_in[1];
    const float* dl = (const float*)d_in[2];
    float* y = (float*)d_out;

    huber_ema_kernel<<<dim3(256), dim3(192), 0, stream>>>(x, la, dl, y);
}